// Round 4
// baseline (626.794 us; speedup 1.0000x reference)
//
#include <hip/hip_runtime.h>
#include <cstdint>
#include <cstddef>

typedef _Float16 f16;
typedef _Float16 half8 __attribute__((ext_vector_type(8)));
typedef float f32x4 __attribute__((ext_vector_type(4)));

constexpr int CDIM = 192, HW = 3136, NBAT = 4, TSTEPS = 16;
constexpr int MTOT = NBAT * HW;       // 12544
constexpr int BM = 32;
constexpr int TPB = MTOT / BM / NBAT; // 98 hw-tiles per batch
constexpr int NBLK = MTOT / BM;       // 392

// workspace: packed weights only
constexpr size_t OFF_WZR = 0;
constexpr size_t SZ_WZR  = (size_t)384 * 384 * 2;
constexpr size_t OFF_WH  = OFF_WZR + SZ_WZR;

// ---------------- weight packing into B-fragment order ----------------
// B[k][n] = w[n][k]; frag: lane=(g<<4)|(n&15), slot i -> k = kt*32+g*8+i
__global__ void pack_w(const float* __restrict__ wz, const float* __restrict__ wr,
                       const float* __restrict__ wh, char* __restrict__ ws) {
    int idx = blockIdx.x * 256 + threadIdx.x;
    const int ZRT = 384 * 384;
    int n, k, NT;
    float w;
    f16* dst;
    if (idx < ZRT) {
        n = idx / 384; k = idx - n * 384;
        w = (n < 192) ? wz[n * 384 + k] : wr[(n - 192) * 384 + k];
        dst = (f16*)(ws + OFF_WZR); NT = 24;
    } else {
        int j = idx - ZRT;
        if (j >= 192 * 384) return;
        n = j / 384; k = j - n * 384;
        w = wh[n * 384 + k];
        dst = (f16*)(ws + OFF_WH); NT = 12;
    }
    int kt = k >> 5, g = (k >> 3) & 3, i = k & 7, nt = n >> 4;
    int lane = (g << 4) | (n & 15);
    dst[((size_t)(kt * NT + nt) * 64 + lane) * 8 + i] = (f16)w;
}

// ---------------- single persistent-per-block kernel: all 16 steps ----------------
// Block = 32 rows (one hw-tile of one batch) x full N=192. 4 waves, wave w owns
// n-columns [48w, 48w+48). h lives in LDS for the whole t-loop (recurrence is
// pointwise in m -> zero cross-block deps -> one launch total).
// LDS tiles [32][192] f16, row stride 384B, XOR swizzle ((row&7)<<4) on in-row byte.
__global__ __launch_bounds__(256, 2) void gru_all(
    const float* __restrict__ video,
    const f16* __restrict__ wZR, const f16* __restrict__ wH,
    const float* __restrict__ bz, const float* __restrict__ br,
    const float* __restrict__ bh, float* __restrict__ dout) {
    __shared__ __align__(16) char smem[36864];
    char* AX = smem;             // [32][192] x_t
    char* AH = smem + 12288;     // [32][192] h   (persistent across steps)
    char* RH = smem + 24576;     // [32][192] r*h
    const int tid = threadIdx.x, w = tid >> 6, lane = tid & 63;
    const int l15 = lane & 15, lg = lane >> 4;
    const int mt = blockIdx.x, bb = mt / TPB, hw0 = (mt % TPB) * BM;
    const int slot = (l15 & 7) << 4;

    // staging coords: thread = (c-group 0..7) x (hw 0..31); 24 channels per group
    const int sh = tid & 31, scg = tid >> 5;
    const int swsh = (sh & 7) << 4;
    const float* vbase = video + (size_t)bb * TSTEPS * CDIM * HW + hw0 + sh;
    float* obase = dout + (size_t)bb * TSTEPS * CDIM * HW + hw0 + sh;

    float vbz[3], vbr[3], vbh[3];
#pragma unroll
    for (int r = 0; r < 3; ++r) {
        int c = w * 48 + r * 16 + l15;
        vbz[r] = bz[c]; vbr[r] = br[c]; vbh[r] = bh[c];
    }

    // h0 = 0 (zeros are swizzle-invariant) ; stage x for t=0
    {
        half8 zz = {};
#pragma unroll
        for (int i = 0; i < 3; ++i) *(half8*)(AH + tid * 48 + i * 16) = zz;
        const float* vs = vbase;
#pragma unroll
        for (int ch = 0; ch < 3; ++ch) {
            half8 hv;
#pragma unroll
            for (int j = 0; j < 8; ++j) hv[j] = (f16)vs[(size_t)(scg * 24 + ch * 8 + j) * HW];
            *(half8*)(AX + sh * 384 + ((scg * 48 + ch * 16) ^ swsh)) = hv;
        }
    }
    __syncthreads();

    for (int t = 0; t < TSTEPS; ++t) {
        // ---- ZR GEMM: barrier-free K-loop (A in LDS, B streamed from L2) ----
        f32x4 az[2][3], ar[2][3];
#pragma unroll
        for (int i = 0; i < 2; ++i)
#pragma unroll
            for (int r = 0; r < 3; ++r)
#pragma unroll
                for (int q = 0; q < 4; ++q) { az[i][r][q] = 0.f; ar[i][r][q] = 0.f; }
#pragma unroll
        for (int kt = 0; kt < 12; ++kt) {
            const char* ab = (kt < 6) ? AX : AH;
            int kb = (kt % 6) * 64 + lg * 16;
            half8 a0 = *(const half8*)(ab + l15 * 384 + (kb ^ slot));
            half8 a1 = *(const half8*)(ab + (16 + l15) * 384 + (kb ^ slot));
#pragma unroll
            for (int r = 0; r < 3; ++r) {
                half8 bzf = *(const half8*)(wZR + ((size_t)(kt * 24 + w * 3 + r) * 64 + lane) * 8);
                half8 brf = *(const half8*)(wZR + ((size_t)(kt * 24 + 12 + w * 3 + r) * 64 + lane) * 8);
                az[0][r] = __builtin_amdgcn_mfma_f32_16x16x32_f16(a0, bzf, az[0][r], 0, 0, 0);
                az[1][r] = __builtin_amdgcn_mfma_f32_16x16x32_f16(a1, bzf, az[1][r], 0, 0, 0);
                ar[0][r] = __builtin_amdgcn_mfma_f32_16x16x32_f16(a0, brf, ar[0][r], 0, 0, 0);
                ar[1][r] = __builtin_amdgcn_mfma_f32_16x16x32_f16(a1, brf, ar[1][r], 0, 0, 0);
            }
        }
        // ---- r*h -> RH (z stays in registers) ; C/D map col=lane&15, row=(lane>>4)*4+q ----
#pragma unroll
        for (int i = 0; i < 2; ++i)
#pragma unroll
            for (int r = 0; r < 3; ++r)
#pragma unroll
                for (int q = 0; q < 4; ++q) {
                    int row = i * 16 + lg * 4 + q;
                    int cb = 2 * (w * 48 + r * 16 + l15);
                    int sw = (row & 7) << 4;
                    float rg = 1.f / (1.f + __expf(-(ar[i][r][q] + vbr[r])));
                    float hv = (float)*(const f16*)(AH + row * 384 + (cb ^ sw));
                    *(f16*)(RH + row * 384 + (cb ^ sw)) = (f16)(rg * hv);
                }
        __syncthreads();

        // ---- H GEMM: A = [x | r*h] ----
        f32x4 ac[2][3];
#pragma unroll
        for (int i = 0; i < 2; ++i)
#pragma unroll
            for (int r = 0; r < 3; ++r)
#pragma unroll
                for (int q = 0; q < 4; ++q) ac[i][r][q] = 0.f;
#pragma unroll
        for (int kt = 0; kt < 12; ++kt) {
            const char* ab = (kt < 6) ? AX : RH;
            int kb = (kt % 6) * 64 + lg * 16;
            half8 a0 = *(const half8*)(ab + l15 * 384 + (kb ^ slot));
            half8 a1 = *(const half8*)(ab + (16 + l15) * 384 + (kb ^ slot));
#pragma unroll
            for (int r = 0; r < 3; ++r) {
                half8 bf = *(const half8*)(wH + ((size_t)(kt * 12 + w * 3 + r) * 64 + lane) * 8);
                ac[0][r] = __builtin_amdgcn_mfma_f32_16x16x32_f16(a0, bf, ac[0][r], 0, 0, 0);
                ac[1][r] = __builtin_amdgcn_mfma_f32_16x16x32_f16(a1, bf, ac[1][r], 0, 0, 0);
            }
        }
        // ---- epilogue: h_new = (1-z)h + z*tanh -> AH in place (each cell owned by 1 thread) ----
#pragma unroll
        for (int i = 0; i < 2; ++i)
#pragma unroll
            for (int r = 0; r < 3; ++r)
#pragma unroll
                for (int q = 0; q < 4; ++q) {
                    int row = i * 16 + lg * 4 + q;
                    int cb = 2 * (w * 48 + r * 16 + l15);
                    int sw = (row & 7) << 4;
                    float zg = 1.f / (1.f + __expf(-(az[i][r][q] + vbz[r])));
                    float e = __expf(2.f * (ac[i][r][q] + vbh[r]));
                    float th = 1.f - 2.f / (e + 1.f);
                    float hold = (float)*(const f16*)(AH + row * 384 + (cb ^ sw));
                    *(f16*)(AH + row * 384 + (cb ^ sw)) = (f16)((1.f - zg) * hold + zg * th);
                }
        __syncthreads();

        // ---- dout writeout (from AH) + stage next x ----
        {
            float* ob = obase + (size_t)t * CDIM * HW;
#pragma unroll
            for (int ch = 0; ch < 3; ++ch) {
                half8 hv = *(const half8*)(AH + sh * 384 + ((scg * 48 + ch * 16) ^ swsh));
#pragma unroll
                for (int j = 0; j < 8; ++j)
                    ob[(size_t)(scg * 24 + ch * 8 + j) * HW] = (float)hv[j];
            }
            if (t < TSTEPS - 1) {
                const float* vs = vbase + (size_t)(t + 1) * CDIM * HW;
#pragma unroll
                for (int ch = 0; ch < 3; ++ch) {
                    half8 hv;
#pragma unroll
                    for (int j = 0; j < 8; ++j) hv[j] = (f16)vs[(size_t)(scg * 24 + ch * 8 + j) * HW];
                    *(half8*)(AX + sh * 384 + ((scg * 48 + ch * 16) ^ swsh)) = hv;
                }
            }
        }
        __syncthreads();
    }
}

extern "C" void kernel_launch(void* const* d_in, const int* in_sizes, int n_in,
                              void* d_out, int out_size, void* d_ws, size_t ws_size,
                              hipStream_t stream) {
    const float* video = (const float*)d_in[0];
    const float* wz = (const float*)d_in[1];
    const float* bz = (const float*)d_in[2];
    const float* wr = (const float*)d_in[3];
    const float* br = (const float*)d_in[4];
    const float* wh = (const float*)d_in[5];
    const float* bh = (const float*)d_in[6];
    char* ws = (char*)d_ws;
    const f16* wZR = (const f16*)(ws + OFF_WZR);
    const f16* wHp = (const f16*)(ws + OFF_WH);
    float* dout = (float*)d_out;

    pack_w<<<864, 256, 0, stream>>>(wz, wr, wh, ws);
    gru_all<<<NBLK, 256, 0, stream>>>(video, wZR, wHp, bz, br, bh, dout);
}

// Round 5
// 354.107 us; speedup vs baseline: 1.7701x; 1.7701x over previous
//
#include <hip/hip_runtime.h>
#include <cstdint>
#include <cstddef>

typedef _Float16 f16;
typedef _Float16 half8 __attribute__((ext_vector_type(8)));
typedef float f32x4 __attribute__((ext_vector_type(4)));

constexpr int CDIM = 192, HW = 3136, NBAT = 4, TSTEPS = 16;
constexpr int MTOT = NBAT * HW;       // 12544
constexpr int BM = 64;
constexpr int TPB = HW / BM;          // 49 hw-tiles per batch
constexpr int NBLK = MTOT / BM;       // 196

// workspace: packed weights only
constexpr size_t OFF_WZR = 0;
constexpr size_t SZ_WZR  = (size_t)384 * 384 * 2;
constexpr size_t OFF_WH  = OFF_WZR + SZ_WZR;

// ---------------- weight packing into B-fragment order ----------------
// B[k][n] = w[n][k]; frag: lane=(g<<4)|(n&15), slot i -> k = kt*32+g*8+i
__global__ void pack_w(const float* __restrict__ wz, const float* __restrict__ wr,
                       const float* __restrict__ wh, char* __restrict__ ws) {
    int idx = blockIdx.x * 256 + threadIdx.x;
    const int ZRT = 384 * 384;
    int n, k, NT;
    float w;
    f16* dst;
    if (idx < ZRT) {
        n = idx / 384; k = idx - n * 384;
        w = (n < 192) ? wz[n * 384 + k] : wr[(n - 192) * 384 + k];
        dst = (f16*)(ws + OFF_WZR); NT = 24;
    } else {
        int j = idx - ZRT;
        if (j >= 192 * 384) return;
        n = j / 384; k = j - n * 384;
        w = wh[n * 384 + k];
        dst = (f16*)(ws + OFF_WH); NT = 12;
    }
    int kt = k >> 5, g = (k >> 3) & 3, i = k & 7, nt = n >> 4;
    int lane = (g << 4) | (n & 15);
    dst[((size_t)(kt * NT + nt) * 64 + lane) * 8 + i] = (f16)w;
}

// ---------------- single-launch persistent kernel: all 16 steps ----------------
// Block = 64 rows (one hw-tile) x full N=192. 4 waves; wave w owns n-cols
// [48w,48w+48) over all 64 rows (4 m-reps) -> half the weight re-reads of BM=32.
// h lives in LDS across the whole t-loop. Video/dout accessed non-temporally so
// the 442KB packed-weight set stays L2-resident.
// LDS tiles [64][192] f16, row stride 384B, XOR swizzle ((row&7)<<4) on in-row byte.
__global__ __launch_bounds__(256) void gru_all(
    const float* __restrict__ video,
    const f16* __restrict__ wZR, const f16* __restrict__ wH,
    const float* __restrict__ bz, const float* __restrict__ br,
    const float* __restrict__ bh, float* __restrict__ dout) {
    __shared__ __align__(16) char smem[73728];
    char* AX = smem;             // [64][192] x_t
    char* AH = smem + 24576;     // [64][192] h (persistent)
    char* RH = smem + 49152;     // [64][192] r*h
    const int tid = threadIdx.x, w = tid >> 6, lane = tid & 63;
    const int l15 = lane & 15, lg = lane >> 4;
    const int mt = blockIdx.x, bb = mt / TPB, hw0 = (mt % TPB) * BM;
    const int slot = (l15 & 7) << 4;
    const int swsh = (lane & 7) << 4;   // staging rows: lane = hw

    const float* vbase = video + (size_t)bb * TSTEPS * CDIM * HW + hw0 + lane;
    float* obase = dout + (size_t)bb * TSTEPS * CDIM * HW + hw0 + lane;

    float vbz[3], vbr[3], vbh[3];
#pragma unroll
    for (int r = 0; r < 3; ++r) {
        int c = w * 48 + r * 16 + l15;
        vbz[r] = bz[c]; vbr[r] = br[c]; vbh[r] = bh[c];
    }

    // h0 = 0 (zeros are swizzle-invariant); stage x for t=0 (wave w = c-group w)
    {
        half8 zz = {};
#pragma unroll
        for (int i = 0; i < 6; ++i) *(half8*)(AH + tid * 96 + i * 16) = zz;
#pragma unroll
        for (int g = 0; g < 6; ++g) {
            half8 hv;
#pragma unroll
            for (int j = 0; j < 8; ++j)
                hv[j] = (f16)__builtin_nontemporal_load(vbase + (size_t)(w * 48 + g * 8 + j) * HW);
            *(half8*)(AX + lane * 384 + ((w * 96 + g * 16) ^ swsh)) = hv;
        }
    }
    __syncthreads();

#pragma unroll 1
    for (int t = 0; t < TSTEPS; ++t) {
        // ---- ZR GEMM: barrier-free K-loop (A in LDS, B streamed via L2) ----
        f32x4 az[4][3], ar[4][3];
#pragma unroll
        for (int i = 0; i < 4; ++i)
#pragma unroll
            for (int r = 0; r < 3; ++r)
#pragma unroll
                for (int q = 0; q < 4; ++q) { az[i][r][q] = 0.f; ar[i][r][q] = 0.f; }
#pragma unroll
        for (int kt = 0; kt < 12; ++kt) {
            const char* ab = (kt < 6) ? AX : AH;
            int kb = (kt % 6) * 64 + lg * 16;
            half8 a[4];
#pragma unroll
            for (int i = 0; i < 4; ++i)
                a[i] = *(const half8*)(ab + (i * 16 + l15) * 384 + (kb ^ slot));
#pragma unroll
            for (int r = 0; r < 3; ++r) {
                half8 bzf = *(const half8*)(wZR + ((size_t)(kt * 24 + w * 3 + r) * 64 + lane) * 8);
                half8 brf = *(const half8*)(wZR + ((size_t)(kt * 24 + 12 + w * 3 + r) * 64 + lane) * 8);
#pragma unroll
                for (int i = 0; i < 4; ++i)
                    az[i][r] = __builtin_amdgcn_mfma_f32_16x16x32_f16(a[i], bzf, az[i][r], 0, 0, 0);
#pragma unroll
                for (int i = 0; i < 4; ++i)
                    ar[i][r] = __builtin_amdgcn_mfma_f32_16x16x32_f16(a[i], brf, ar[i][r], 0, 0, 0);
            }
        }

        // ---- T14 async-stage: issue next-step x loads now, LDS-write after barrier ----
        float xn[6][8];
        if (t + 1 < TSTEPS) {
            const float* vs = vbase + (size_t)(t + 1) * CDIM * HW;
#pragma unroll
            for (int g = 0; g < 6; ++g)
#pragma unroll
                for (int j = 0; j < 8; ++j)
                    xn[g][j] = __builtin_nontemporal_load(vs + (size_t)(w * 48 + g * 8 + j) * HW);
        }

        // ---- r*h -> RH (z stays in regs); C/D map col=lane&15, row=(lane>>4)*4+q ----
#pragma unroll
        for (int i = 0; i < 4; ++i)
#pragma unroll
            for (int r = 0; r < 3; ++r)
#pragma unroll
                for (int q = 0; q < 4; ++q) {
                    int row = i * 16 + lg * 4 + q;
                    int cb = 2 * (w * 48 + r * 16 + l15);
                    int sw = (row & 7) << 4;
                    float rg = 1.f / (1.f + __expf(-(ar[i][r][q] + vbr[r])));
                    float hv = (float)*(const f16*)(AH + row * 384 + (cb ^ sw));
                    *(f16*)(RH + row * 384 + (cb ^ sw)) = (f16)(rg * hv);
                }
        __syncthreads();

        // ---- H GEMM: A = [x | r*h] ----
        f32x4 ac[4][3];
#pragma unroll
        for (int i = 0; i < 4; ++i)
#pragma unroll
            for (int r = 0; r < 3; ++r)
#pragma unroll
                for (int q = 0; q < 4; ++q) ac[i][r][q] = 0.f;
#pragma unroll
        for (int kt = 0; kt < 12; ++kt) {
            const char* ab = (kt < 6) ? AX : RH;
            int kb = (kt % 6) * 64 + lg * 16;
            half8 a[4];
#pragma unroll
            for (int i = 0; i < 4; ++i)
                a[i] = *(const half8*)(ab + (i * 16 + l15) * 384 + (kb ^ slot));
#pragma unroll
            for (int r = 0; r < 3; ++r) {
                half8 bf = *(const half8*)(wH + ((size_t)(kt * 12 + w * 3 + r) * 64 + lane) * 8);
#pragma unroll
                for (int i = 0; i < 4; ++i)
                    ac[i][r] = __builtin_amdgcn_mfma_f32_16x16x32_f16(a[i], bf, ac[i][r], 0, 0, 0);
            }
        }

        // ---- epilogue: h_new = (1-z)h + z*tanh -> AH in place (thread-owned cells) ----
#pragma unroll
        for (int i = 0; i < 4; ++i)
#pragma unroll
            for (int r = 0; r < 3; ++r)
#pragma unroll
                for (int q = 0; q < 4; ++q) {
                    int row = i * 16 + lg * 4 + q;
                    int cb = 2 * (w * 48 + r * 16 + l15);
                    int sw = (row & 7) << 4;
                    float zg = 1.f / (1.f + __expf(-(az[i][r][q] + vbz[r])));
                    float e = __expf(2.f * (ac[i][r][q] + vbh[r]));
                    float th = 1.f - 2.f / (e + 1.f);
                    float hold = (float)*(const f16*)(AH + row * 384 + (cb ^ sw));
                    *(f16*)(AH + row * 384 + (cb ^ sw)) = (f16)((1.f - zg) * hold + zg * th);
                }
        __syncthreads();   // AH final; AX free (H loop done)

        // ---- dout writeout (nt stores) + restage AX from prefetched regs ----
        {
            float* ob = obase + (size_t)t * CDIM * HW;
#pragma unroll
            for (int g = 0; g < 6; ++g) {
                half8 hv = *(const half8*)(AH + lane * 384 + ((w * 96 + g * 16) ^ swsh));
#pragma unroll
                for (int j = 0; j < 8; ++j)
                    __builtin_nontemporal_store((float)hv[j], ob + (size_t)(w * 48 + g * 8 + j) * HW);
            }
            if (t + 1 < TSTEPS) {
#pragma unroll
                for (int g = 0; g < 6; ++g) {
                    half8 o;
#pragma unroll
                    for (int j = 0; j < 8; ++j) o[j] = (f16)xn[g][j];
                    *(half8*)(AX + lane * 384 + ((w * 96 + g * 16) ^ swsh)) = o;
                }
            }
        }
        __syncthreads();
    }
}

extern "C" void kernel_launch(void* const* d_in, const int* in_sizes, int n_in,
                              void* d_out, int out_size, void* d_ws, size_t ws_size,
                              hipStream_t stream) {
    const float* video = (const float*)d_in[0];
    const float* wz = (const float*)d_in[1];
    const float* bz = (const float*)d_in[2];
    const float* wr = (const float*)d_in[3];
    const float* br = (const float*)d_in[4];
    const float* wh = (const float*)d_in[5];
    const float* bh = (const float*)d_in[6];
    char* ws = (char*)d_ws;
    const f16* wZR = (const f16*)(ws + OFF_WZR);
    const f16* wHp = (const f16*)(ws + OFF_WH);
    float* dout = (float*)d_out;

    pack_w<<<864, 256, 0, stream>>>(wz, wr, wh, ws);
    gru_all<<<NBLK, 256, 0, stream>>>(video, wZR, wHp, bz, br, bh, dout);
}